// Round 2
// baseline (1240.421 us; speedup 1.0000x reference)
//
#include <hip/hip_runtime.h>
#include <hip/hip_bf16.h>
#include <math.h>

// Problem constants
#define NB    64
#define D     256
#define K     1024
#define HW    1024
#define NTOT  65536
// phase-1 (bf16x3 MFMA) score error ~1.5e-7 (sigma). 1e-5 is ~60 sigma and
// ~10x tighter than the top-2 gap scale (~1e-5) of this near-uniform codebook,
// so the fp64 rescue set shrinks ~10x vs MARGIN=1e-4.
#define MARGIN 1e-5f

// Output layout (floats)
#define OUT_QOUT   1
#define OUT_PERP   16777217
#define OUT_ENC    16777218
#define OUT_QFLAT  83886082

// ws layout (bytes):
//   0      int rcount
//   16     int hist[1024]
//   4112   float enorm[1024]
//   8208   int idx[65536]            -> 270352
//   270352 int rlist[65536]          -> 532496
//   532496 double lossPartial[2048]  -> 548880
//   548880 ushort efrag[524288]      -> 1597456   (bf16 fragment-layout E, hi+lo)
// efrag layout: [h(2)][ntg(64)][dc(8)][lane(64)][j(8)] bf16
//   element = split_h( emb[ k = ntg*16 + (lane&15) ][ d = dc*32 + (lane>>4)*8 + j ] )

typedef __attribute__((ext_vector_type(8))) short bf16x8;
typedef __attribute__((ext_vector_type(4))) float f32x4;

__global__ void enorm_kernel(const float* __restrict__ emb, float* __restrict__ enorm) {
    int k = blockIdx.x * 256 + threadIdx.x;
    const float4* row = (const float4*)(emb + (size_t)k * D);
    float s = 0.f;
    #pragma unroll
    for (int q = 0; q < D / 4; q++) {
        float4 v = row[q];
        s += v.x * v.x + v.y * v.y + v.z * v.z + v.w * v.w;
    }
    enorm[k] = s;
}

// ---- Pre-split E into MFMA B-fragment layout (hi/lo bf16), once ----
__global__ void esplit_kernel(const float* __restrict__ emb, ushort* __restrict__ efrag) {
    const int ntg = blockIdx.x;          // 64 blocks: one 16-col k-tile each
    const int t = threadIdx.x;
    __shared__ float sEm[16 * 260];      // 16 rows x 256 d, pad 4

    // stage emb rows k = ntg*16 .. +15
    {
        const int row = t >> 4, seg = t & 15;
        const float4* src = (const float4*)(emb + (size_t)(ntg * 16 + row) * D + seg * 16);
        float4* dst = (float4*)(sEm + row * 260 + seg * 16);
        #pragma unroll
        for (int q = 0; q < 4; q++) dst[q] = src[q];
    }
    __syncthreads();

    const int w = t >> 6, lane = t & 63;
    for (int fb = w; fb < 16; fb += 4) {         // fb = h*8 + dc
        const int h = fb >> 3, dc = fb & 7;
        const float* srcp = sEm + (lane & 15) * 260 + dc * 32 + (lane >> 4) * 8;
        ushort o[8];
        #pragma unroll
        for (int j = 0; j < 8; j++) {
            float x = srcp[j];
            __hip_bfloat16 hb = __float2bfloat16(x);
            if (h == 0) { o[j] = *(ushort*)&hb; }
            else {
                float hf = __bfloat162float(hb);
                __hip_bfloat16 lb = __float2bfloat16(x - hf);
                o[j] = *(ushort*)&lb;
            }
        }
        ushort* dst = efrag + ((size_t)(h * 64 + ntg) * 8 + dc) * 512 + lane * 8;
        *(int4*)dst = *(int4*)o;
    }
}

// ---- Phase 1: MFMA bf16x3 scores + in-kernel argmin (min1, idx, min2) ----
// 32 rows/block (LDS 32KB -> 4 blocks/CU), 4 waves; each wave: 2 m-tiles x 4 n-tiles,
// waves split K. Prefetch only bh (bl loaded in-loop, hidden behind the 2 MFMAs
// that don't consume it). Arch-VGPR demand ~110 < 128 cap -> no scratch.
__global__ __launch_bounds__(256, 4) void score_mfma_kernel(
    const float* __restrict__ in, const ushort* __restrict__ efrag,
    const float* __restrict__ enorm, int* __restrict__ idx,
    int* __restrict__ rcount, int* __restrict__ rlist)
{
    __shared__ ushort sA[16384];   // [h(2)][mt(2)][dc(8)][lane(64)][j(8)] bf16 = 32KB

    const int t = threadIdx.x;
    const int n0 = blockIdx.x * 32;
    const int b = n0 >> 10, p0 = n0 & 1023;

    // Stage A: thread t owns d=t, all 32 rows; convert to hi/lo, write fragment layout.
    {
        const float* src = in + (size_t)b * (D * HW) + (size_t)t * HW + p0;
        const int quad = (t >> 3) & 3, dc = t >> 5, j = t & 7;
        #pragma unroll
        for (int g = 0; g < 2; g++) {                  // mt = g
            float xs[16];
            #pragma unroll
            for (int q = 0; q < 4; q++) {
                float4 v = ((const float4*)src)[g * 4 + q];
                xs[q * 4 + 0] = v.x; xs[q * 4 + 1] = v.y; xs[q * 4 + 2] = v.z; xs[q * 4 + 3] = v.w;
            }
            #pragma unroll
            for (int mm = 0; mm < 16; mm++) {
                float x = xs[mm];
                __hip_bfloat16 hb = __float2bfloat16(x);
                float hf = __bfloat162float(hb);
                __hip_bfloat16 lb = __float2bfloat16(x - hf);
                const int l = mm + 16 * quad;
                sA[((0 * 2 + g) * 8 + dc) * 512 + l * 8 + j] = *(ushort*)&hb;
                sA[((1 * 2 + g) * 8 + dc) * 512 + l * 8 + j] = *(ushort*)&lb;
            }
        }
    }
    __syncthreads();

    const int w = t >> 6, lane = t & 63;

    // this lane's running argmin for its ONE owned row:
    //   owned (mt,r) = ((lane&15)>>2, lane&3), valid when (lane&15)<8;
    //   row = mt*16 + (lane>>4)*4 + r
    float rm1 = 3.4e38f, rm2 = 3.4e38f; int ri = 0;

    for (int kp = 0; kp < 4; kp++) {
        f32x4 acc[2][4];
        #pragma unroll
        for (int mt = 0; mt < 2; mt++)
            #pragma unroll
            for (int ntl = 0; ntl < 4; ntl++) acc[mt][ntl] = (f32x4){0.f, 0.f, 0.f, 0.f};

        // B hi frags prefetched one dc ahead; lo frags loaded on demand.
        bf16x8 bh[4], nbh[4];
        #pragma unroll
        for (int ntl = 0; ntl < 4; ntl++) {
            const int ntg = kp * 16 + w * 4 + ntl;
            bh[ntl] = *(const bf16x8*)(efrag + ((size_t)ntg * 8 + 0) * 512 + lane * 8);
        }
        for (int dc = 0; dc < 8; dc++) {
            bf16x8 bl[4];
            #pragma unroll
            for (int ntl = 0; ntl < 4; ntl++) {
                const int ntg = kp * 16 + w * 4 + ntl;
                const size_t off = ((size_t)ntg * 8 + dc) * 512 + lane * 8;
                bl[ntl] = *(const bf16x8*)(efrag + off + 262144);
                if (dc < 7) nbh[ntl] = *(const bf16x8*)(efrag + off + 512);
            }
            #pragma unroll
            for (int mt = 0; mt < 2; mt++) {
                bf16x8 ah = *(const bf16x8*)(sA + ((0 * 2 + mt) * 8 + dc) * 512 + lane * 8);
                bf16x8 al = *(const bf16x8*)(sA + ((1 * 2 + mt) * 8 + dc) * 512 + lane * 8);
                #pragma unroll
                for (int ntl = 0; ntl < 4; ntl++) {
                    acc[mt][ntl] = __builtin_amdgcn_mfma_f32_16x16x32_bf16(al, bh[ntl], acc[mt][ntl], 0, 0, 0);
                    acc[mt][ntl] = __builtin_amdgcn_mfma_f32_16x16x32_bf16(ah, bh[ntl], acc[mt][ntl], 0, 0, 0);
                    acc[mt][ntl] = __builtin_amdgcn_mfma_f32_16x16x32_bf16(ah, bl[ntl], acc[mt][ntl], 0, 0, 0);
                }
            }
            if (dc < 7) {
                #pragma unroll
                for (int ntl = 0; ntl < 4; ntl++) bh[ntl] = nbh[ntl];
            }
        }

        // epilogue: scores + per-row reduce (16 lanes per quad hold 16 k-cols of one row);
        // after the butterfly all 16 quad lanes hold the reduced triple -> owner lane merges.
        float env[4]; int kc[4];
        #pragma unroll
        for (int ntl = 0; ntl < 4; ntl++) {
            kc[ntl] = kp * 256 + (w * 4 + ntl) * 16 + (lane & 15);
            env[ntl] = enorm[kc[ntl]];
        }
        #pragma unroll
        for (int mt = 0; mt < 2; mt++)
            #pragma unroll
            for (int r = 0; r < 4; r++) {
                float m1 = 3.4e38f, m2 = 3.4e38f; int i1 = 0;
                #pragma unroll
                for (int ntl = 0; ntl < 4; ntl++) {
                    float s = env[ntl] - 2.0f * acc[mt][ntl][r];
                    if (s < m1) { m2 = m1; m1 = s; i1 = kc[ntl]; }
                    else if (s < m2) m2 = s;
                }
                #pragma unroll
                for (int mask = 1; mask <= 8; mask <<= 1) {
                    float o1 = __shfl_xor(m1, mask, 64);
                    int   oi = __shfl_xor(i1, mask, 64);
                    float o2 = __shfl_xor(m2, mask, 64);
                    float n2 = fminf(fminf(m2, o2), fmaxf(m1, o1));
                    if (o1 < m1 || (o1 == m1 && oi < i1)) { m1 = o1; i1 = oi; }
                    m2 = n2;
                }
                if ((lane & 15) == mt * 4 + r) {
                    float n2 = fminf(fminf(rm2, m2), fmaxf(rm1, m1));
                    if (m1 < rm1 || (m1 == rm1 && i1 < ri)) { rm1 = m1; ri = i1; }
                    rm2 = n2;
                }
            }
    }

    // cross-wave merge via LDS (alias sA; all MFMA A-reads done)
    __syncthreads();
    float* sM1 = (float*)sA;           // [4][32]
    float* sM2 = sM1 + 128;
    int*   sI  = (int*)(sM2 + 128);
    if ((lane & 15) < 8) {
        const int row = ((lane & 15) >> 2) * 16 + (lane >> 4) * 4 + (lane & 3);
        sM1[w * 32 + row] = rm1;
        sM2[w * 32 + row] = rm2;
        sI [w * 32 + row] = ri;
    }
    __syncthreads();
    if (t < 32) {
        float b1 = sM1[t], b2 = sM2[t]; int bi = sI[t];
        #pragma unroll
        for (int ww = 1; ww < 4; ww++) {
            float a1 = sM1[ww * 32 + t], a2 = sM2[ww * 32 + t]; int ai = sI[ww * 32 + t];
            float n2 = fminf(fminf(b2, a2), fmaxf(b1, a1));
            if (a1 < b1 || (a1 == b1 && ai < bi)) { b1 = a1; bi = ai; }
            b2 = n2;
        }
        const int n = n0 + t;
        idx[n] = bi;
        if (b2 - b1 < MARGIN) {
            int pos = atomicAdd(rcount, 1);
            rlist[pos] = n;
        }
    }
}

// ---- Phase 2: fp64 re-score of ambiguous rows (true argmin, lowest-idx ties) ----
// shfl hoisted out of the k-loop; 16 running sums per lane.
__global__ void rescue_kernel(const float* __restrict__ in, const float* __restrict__ emb,
                              const int* __restrict__ rcount, const int* __restrict__ rlist,
                              int* __restrict__ idx)
{
    const int wid = blockIdx.x * 4 + (threadIdx.x >> 6);
    const int lane = threadIdx.x & 63;
    const int count = *rcount;
    for (int li = wid; li < count; li += 512 * 4) {
        const int n = rlist[li];
        const int b = n >> 10, p = n & 1023;
        const float* f = in + (size_t)b * (D * HW) + p;
        float fr[4];
        #pragma unroll
        for (int q = 0; q < 4; q++) fr[q] = f[(size_t)(lane + q * 64) * HW];
        double s[16];
        #pragma unroll
        for (int kk = 0; kk < 16; kk++) s[kk] = 0.0;
        for (int q = 0; q < 4; q++) {
            for (int dl = 0; dl < 64; dl++) {
                const double fv = (double)__shfl(fr[q], dl, 64);
                const int d = q * 64 + dl;
                #pragma unroll
                for (int kk = 0; kk < 16; kk++) {
                    const double ev = (double)emb[(size_t)(lane + kk * 64) * D + d];
                    s[kk] += ev * (ev - 2.0 * fv);
                }
            }
        }
        double bm = 1e300; int bk = 0;
        #pragma unroll
        for (int kk = 0; kk < 16; kk++) {         // kk ascending -> lowest k on ties
            const int k = lane + kk * 64;
            if (s[kk] < bm) { bm = s[kk]; bk = k; }
        }
        #pragma unroll
        for (int off = 32; off >= 1; off >>= 1) {
            double om = __shfl_xor(bm, off, 64);
            int    ok = __shfl_xor(bk, off, 64);
            if (om < bm || (om == bm && ok < bk)) { bm = om; bk = ok; }
        }
        if (lane == 0) idx[n] = bk;
    }
}

// ---- Fused outputs: qout(NCHW) + loss partials + qflat + FULL one-hot + hist ----
// Block = 32 rows x 256 d, emb rows staged in LDS (coalesced gather).
// enc is written densely here (268MB streamed) -> the separate 268MB memset pass is gone.
__global__ __launch_bounds__(256) void outputs_kernel(
    const float* __restrict__ in, const float* __restrict__ emb,
    const int* __restrict__ idx, float* __restrict__ out,
    double* __restrict__ lossPartial, int* __restrict__ hist)
{
    __shared__ int skv[32];
    __shared__ float sQ[32 * 260];
    __shared__ double sred[4];

    const int t = threadIdx.x;
    const int n0 = blockIdx.x * 32;
    const int b = n0 >> 10, p0 = n0 & 1023;

    if (t < 32) skv[t] = idx[n0 + t];
    __syncthreads();

    // stage emb rows (coalesced per 8-thread group) + write qflat directly
    {
        const int r = t >> 3, c0 = (t & 7) * 32;
        const int kv = skv[r];
        const float4* src = (const float4*)(emb + (size_t)kv * D + c0);
        float4* dstL = (float4*)(sQ + r * 260 + c0);
        float4* dstG = (float4*)(out + OUT_QFLAT + (size_t)(n0 + r) * D + c0);
        #pragma unroll
        for (int g = 0; g < 8; g++) {
            float4 v = src[g];
            dstL[g] = v;
            dstG[g] = v;
        }
    }
    // enc one-hot: dense coalesced write (thread t owns cols [4t,4t+4) of every row)
    {
        float* encBase = out + OUT_ENC + (size_t)n0 * K;
        const int c0 = t * 4;
        #pragma unroll 4
        for (int r = 0; r < 32; r++) {
            const int kv = skv[r];
            float4 v = make_float4(0.f, 0.f, 0.f, 0.f);
            if (kv >= c0 && kv < c0 + 4) ((float*)&v)[kv - c0] = 1.0f;
            *(float4*)(encBase + (size_t)r * K + c0) = v;
        }
    }
    if (t < 32) atomicAdd(&hist[skv[t]], 1);
    __syncthreads();

    // qout NCHW + loss: lanes cover p (coalesced 128B per 32-lane group)
    const int p = t & 31, dg = t >> 5;
    double acc = 0.0;
    const size_t obase = (size_t)b * (D * HW) + p0 + p;
    #pragma unroll
    for (int dd = 0; dd < 32; dd++) {
        const int d = dg * 32 + dd;
        const float q = sQ[p * 260 + d];
        const float x = in[obase + (size_t)d * HW];
        out[OUT_QOUT + obase + (size_t)d * HW] = q;
        const float df = q - x;
        acc += (double)(df * df);
    }
    #pragma unroll
    for (int off = 32; off >= 1; off >>= 1) acc += __shfl_xor(acc, off, 64);
    if ((t & 63) == 0) sred[t >> 6] = acc;
    __syncthreads();
    if (t == 0) lossPartial[blockIdx.x] = sred[0] + sred[1] + sred[2] + sred[3];
}

__global__ void finalize_kernel(const int* __restrict__ hist, const double* __restrict__ lossPartial,
                                float* __restrict__ out)
{
    const int t = threadIdx.x;
    double s = 0.0;
    #pragma unroll
    for (int q = 0; q < 4; q++) {
        const int c = hist[t + q * 256];
        const double p = (double)c / (double)NTOT;
        s += p * log(p + 1e-10);
    }
    double l = 0.0;
    #pragma unroll
    for (int q = 0; q < 8; q++) l += lossPartial[t + q * 256];
    #pragma unroll
    for (int off = 32; off >= 1; off >>= 1) {
        s += __shfl_xor(s, off, 64);
        l += __shfl_xor(l, off, 64);
    }
    __shared__ double sr[4], lr[4];
    if ((t & 63) == 0) { sr[t >> 6] = s; lr[t >> 6] = l; }
    __syncthreads();
    if (t == 0) {
        out[0] = (float)(1.25 * (lr[0] + lr[1] + lr[2] + lr[3]) / (double)(NTOT * (size_t)D));
        out[OUT_PERP] = (float)exp(-(sr[0] + sr[1] + sr[2] + sr[3]));
    }
}

extern "C" void kernel_launch(void* const* d_in, const int* in_sizes, int n_in,
                              void* d_out, int out_size, void* d_ws, size_t ws_size,
                              hipStream_t stream)
{
    const float* in  = (const float*)d_in[0];   // [64,256,32,32] fp32
    const float* emb = (const float*)d_in[1];   // [1024,256] fp32
    float* out = (float*)d_out;
    char* ws = (char*)d_ws;

    int*    rcount      = (int*)(ws + 0);
    int*    hist        = (int*)(ws + 16);
    float*  enorm       = (float*)(ws + 4112);
    int*    idx         = (int*)(ws + 8208);
    int*    rlist       = (int*)(ws + 270352);
    double* lossPartial = (double*)(ws + 532496);
    ushort* efrag       = (ushort*)(ws + 548880);

    hipMemsetAsync(ws, 0, 8208, stream);                                   // rcount + hist

    enorm_kernel<<<K / 256, 256, 0, stream>>>(emb, enorm);
    esplit_kernel<<<K / 16, 256, 0, stream>>>(emb, efrag);
    score_mfma_kernel<<<NTOT / 32, 256, 0, stream>>>(in, efrag, enorm, idx, rcount, rlist);
    rescue_kernel<<<512, 256, 0, stream>>>(in, emb, rcount, rlist, idx);
    outputs_kernel<<<NTOT / 32, 256, 0, stream>>>(in, emb, idx, out, lossPartial, hist);
    finalize_kernel<<<1, 256, 0, stream>>>(hist, lossPartial, out);
}

// Round 3
// 1009.816 us; speedup vs baseline: 1.2284x; 1.2284x over previous
//
#include <hip/hip_runtime.h>
#include <hip/hip_bf16.h>
#include <math.h>

// Problem constants
#define NB    64
#define D     256
#define K     1024
#define HW    1024
#define NTOT  65536
// phase-1 (bf16x3 MFMA) score error ~1.5e-7 (sigma). 1e-5 is ~60 sigma; rescue
// count ~200 rows (confirmed round 2: occupancy 1.3%, FETCH 5.8MB).
#define MARGIN 1e-5f

// Output layout (floats)
#define OUT_QOUT   1
#define OUT_PERP   16777217
#define OUT_ENC    16777218
#define OUT_QFLAT  83886082

// ws layout (bytes):
//   0      int rcount
//   16     int hist[1024]
//   4112   float enorm[1024]
//   8208   int idx[65536]            -> 270352
//   270352 int rlist[65536]          -> 532496
//   532496 double lossPartial[2048]  -> 548880
//   548880 ushort efrag[524288]      -> 1597456   (bf16 fragment-layout E, hi+lo)
// efrag layout: [h(2)][ntg(64)][dc(8)][lane(64)][j(8)] bf16
//   element = split_h( emb[ k = ntg*16 + (lane&15) ][ d = dc*32 + (lane>>4)*8 + j ] )

typedef __attribute__((ext_vector_type(8))) short bf16x8;
typedef __attribute__((ext_vector_type(4))) float f32x4;

__global__ void enorm_kernel(const float* __restrict__ emb, float* __restrict__ enorm) {
    int k = blockIdx.x * 256 + threadIdx.x;
    const float4* row = (const float4*)(emb + (size_t)k * D);
    float s = 0.f;
    #pragma unroll
    for (int q = 0; q < D / 4; q++) {
        float4 v = row[q];
        s += v.x * v.x + v.y * v.y + v.z * v.z + v.w * v.w;
    }
    enorm[k] = s;
}

// ---- Pre-split E into MFMA B-fragment layout (hi/lo bf16), once ----
__global__ void esplit_kernel(const float* __restrict__ emb, ushort* __restrict__ efrag) {
    const int ntg = blockIdx.x;          // 64 blocks: one 16-col k-tile each
    const int t = threadIdx.x;
    __shared__ float sEm[16 * 260];      // 16 rows x 256 d, pad 4

    // stage emb rows k = ntg*16 .. +15
    {
        const int row = t >> 4, seg = t & 15;
        const float4* src = (const float4*)(emb + (size_t)(ntg * 16 + row) * D + seg * 16);
        float4* dst = (float4*)(sEm + row * 260 + seg * 16);
        #pragma unroll
        for (int q = 0; q < 4; q++) dst[q] = src[q];
    }
    __syncthreads();

    const int w = t >> 6, lane = t & 63;
    for (int fb = w; fb < 16; fb += 4) {         // fb = h*8 + dc
        const int h = fb >> 3, dc = fb & 7;
        const float* srcp = sEm + (lane & 15) * 260 + dc * 32 + (lane >> 4) * 8;
        ushort o[8];
        #pragma unroll
        for (int j = 0; j < 8; j++) {
            float x = srcp[j];
            __hip_bfloat16 hb = __float2bfloat16(x);
            if (h == 0) { o[j] = *(ushort*)&hb; }
            else {
                float hf = __bfloat162float(hb);
                __hip_bfloat16 lb = __float2bfloat16(x - hf);
                o[j] = *(ushort*)&lb;
            }
        }
        ushort* dst = efrag + ((size_t)(h * 64 + ntg) * 8 + dc) * 512 + lane * 8;
        *(int4*)dst = *(int4*)o;
    }
}

// ---- Phase 1: MFMA bf16x3 scores + in-kernel argmin (min1, idx, min2) ----
// 32 rows/block (LDS 32KB -> 4 blocks/CU), 4 waves; each wave: 2 m-tiles x 4 n-tiles,
// waves split K. Prefetch only bh (bl loaded in-loop, hidden behind the 2 MFMAs
// that don't consume it). Arch-VGPR demand ~110 < 128 cap -> no scratch.
__global__ __launch_bounds__(256, 4) void score_mfma_kernel(
    const float* __restrict__ in, const ushort* __restrict__ efrag,
    const float* __restrict__ enorm, int* __restrict__ idx,
    int* __restrict__ rcount, int* __restrict__ rlist)
{
    __shared__ ushort sA[16384];   // [h(2)][mt(2)][dc(8)][lane(64)][j(8)] bf16 = 32KB

    const int t = threadIdx.x;
    const int n0 = blockIdx.x * 32;
    const int b = n0 >> 10, p0 = n0 & 1023;

    // Stage A: thread t owns d=t, all 32 rows; convert to hi/lo, write fragment layout.
    {
        const float* src = in + (size_t)b * (D * HW) + (size_t)t * HW + p0;
        const int quad = (t >> 3) & 3, dc = t >> 5, j = t & 7;
        #pragma unroll
        for (int g = 0; g < 2; g++) {                  // mt = g
            float xs[16];
            #pragma unroll
            for (int q = 0; q < 4; q++) {
                float4 v = ((const float4*)src)[g * 4 + q];
                xs[q * 4 + 0] = v.x; xs[q * 4 + 1] = v.y; xs[q * 4 + 2] = v.z; xs[q * 4 + 3] = v.w;
            }
            #pragma unroll
            for (int mm = 0; mm < 16; mm++) {
                float x = xs[mm];
                __hip_bfloat16 hb = __float2bfloat16(x);
                float hf = __bfloat162float(hb);
                __hip_bfloat16 lb = __float2bfloat16(x - hf);
                const int l = mm + 16 * quad;
                sA[((0 * 2 + g) * 8 + dc) * 512 + l * 8 + j] = *(ushort*)&hb;
                sA[((1 * 2 + g) * 8 + dc) * 512 + l * 8 + j] = *(ushort*)&lb;
            }
        }
    }
    __syncthreads();

    const int w = t >> 6, lane = t & 63;

    // this lane's running argmin for its ONE owned row:
    //   owned (mt,r) = ((lane&15)>>2, lane&3), valid when (lane&15)<8;
    //   row = mt*16 + (lane>>4)*4 + r
    float rm1 = 3.4e38f, rm2 = 3.4e38f; int ri = 0;

    for (int kp = 0; kp < 4; kp++) {
        f32x4 acc[2][4];
        #pragma unroll
        for (int mt = 0; mt < 2; mt++)
            #pragma unroll
            for (int ntl = 0; ntl < 4; ntl++) acc[mt][ntl] = (f32x4){0.f, 0.f, 0.f, 0.f};

        // B hi frags prefetched one dc ahead; lo frags loaded on demand.
        bf16x8 bh[4], nbh[4];
        #pragma unroll
        for (int ntl = 0; ntl < 4; ntl++) {
            const int ntg = kp * 16 + w * 4 + ntl;
            bh[ntl] = *(const bf16x8*)(efrag + ((size_t)ntg * 8 + 0) * 512 + lane * 8);
        }
        for (int dc = 0; dc < 8; dc++) {
            bf16x8 bl[4];
            #pragma unroll
            for (int ntl = 0; ntl < 4; ntl++) {
                const int ntg = kp * 16 + w * 4 + ntl;
                const size_t off = ((size_t)ntg * 8 + dc) * 512 + lane * 8;
                bl[ntl] = *(const bf16x8*)(efrag + off + 262144);
                if (dc < 7) nbh[ntl] = *(const bf16x8*)(efrag + off + 512);
            }
            #pragma unroll
            for (int mt = 0; mt < 2; mt++) {
                bf16x8 ah = *(const bf16x8*)(sA + ((0 * 2 + mt) * 8 + dc) * 512 + lane * 8);
                bf16x8 al = *(const bf16x8*)(sA + ((1 * 2 + mt) * 8 + dc) * 512 + lane * 8);
                #pragma unroll
                for (int ntl = 0; ntl < 4; ntl++) {
                    acc[mt][ntl] = __builtin_amdgcn_mfma_f32_16x16x32_bf16(al, bh[ntl], acc[mt][ntl], 0, 0, 0);
                    acc[mt][ntl] = __builtin_amdgcn_mfma_f32_16x16x32_bf16(ah, bh[ntl], acc[mt][ntl], 0, 0, 0);
                    acc[mt][ntl] = __builtin_amdgcn_mfma_f32_16x16x32_bf16(ah, bl[ntl], acc[mt][ntl], 0, 0, 0);
                }
            }
            if (dc < 7) {
                #pragma unroll
                for (int ntl = 0; ntl < 4; ntl++) bh[ntl] = nbh[ntl];
            }
        }

        // epilogue: scores + per-row reduce (16 lanes per quad hold 16 k-cols of one row);
        // after the butterfly all 16 quad lanes hold the reduced triple -> owner lane merges.
        float env[4]; int kc[4];
        #pragma unroll
        for (int ntl = 0; ntl < 4; ntl++) {
            kc[ntl] = kp * 256 + (w * 4 + ntl) * 16 + (lane & 15);
            env[ntl] = enorm[kc[ntl]];
        }
        #pragma unroll
        for (int mt = 0; mt < 2; mt++)
            #pragma unroll
            for (int r = 0; r < 4; r++) {
                float m1 = 3.4e38f, m2 = 3.4e38f; int i1 = 0;
                #pragma unroll
                for (int ntl = 0; ntl < 4; ntl++) {
                    float s = env[ntl] - 2.0f * acc[mt][ntl][r];
                    if (s < m1) { m2 = m1; m1 = s; i1 = kc[ntl]; }
                    else if (s < m2) m2 = s;
                }
                #pragma unroll
                for (int mask = 1; mask <= 8; mask <<= 1) {
                    float o1 = __shfl_xor(m1, mask, 64);
                    int   oi = __shfl_xor(i1, mask, 64);
                    float o2 = __shfl_xor(m2, mask, 64);
                    float n2 = fminf(fminf(m2, o2), fmaxf(m1, o1));
                    if (o1 < m1 || (o1 == m1 && oi < i1)) { m1 = o1; i1 = oi; }
                    m2 = n2;
                }
                if ((lane & 15) == mt * 4 + r) {
                    float n2 = fminf(fminf(rm2, m2), fmaxf(rm1, m1));
                    if (m1 < rm1 || (m1 == rm1 && i1 < ri)) { rm1 = m1; ri = i1; }
                    rm2 = n2;
                }
            }
    }

    // cross-wave merge via LDS (alias sA; all MFMA A-reads done)
    __syncthreads();
    float* sM1 = (float*)sA;           // [4][32]
    float* sM2 = sM1 + 128;
    int*   sI  = (int*)(sM2 + 128);
    if ((lane & 15) < 8) {
        const int row = ((lane & 15) >> 2) * 16 + (lane >> 4) * 4 + (lane & 3);
        sM1[w * 32 + row] = rm1;
        sM2[w * 32 + row] = rm2;
        sI [w * 32 + row] = ri;
    }
    __syncthreads();
    if (t < 32) {
        float b1 = sM1[t], b2 = sM2[t]; int bi = sI[t];
        #pragma unroll
        for (int ww = 1; ww < 4; ww++) {
            float a1 = sM1[ww * 32 + t], a2 = sM2[ww * 32 + t]; int ai = sI[ww * 32 + t];
            float n2 = fminf(fminf(b2, a2), fmaxf(b1, a1));
            if (a1 < b1 || (a1 == b1 && ai < bi)) { b1 = a1; bi = ai; }
            b2 = n2;
        }
        const int n = n0 + t;
        idx[n] = bi;
        if (b2 - b1 < MARGIN) {
            int pos = atomicAdd(rcount, 1);
            rlist[pos] = n;
        }
    }
}

// ---- Phase 2: fp64 re-score of ambiguous rows (true argmin, lowest-idx ties) ----
// kk OUTER (contiguous per-lane emb walk -> 16x L1 line reuse; round-2's kk-inner
// order gathered 64 distinct lines/instr and cost 456us of pure latency).
// float4 loads (16 lines/instr), shfl with compile-time lane -> v_readlane/SGPR
// broadcast, 4 independent fp64 chains to break the accumulation dependency.
__global__ void rescue_kernel(const float* __restrict__ in, const float* __restrict__ emb,
                              const int* __restrict__ rcount, const int* __restrict__ rlist,
                              int* __restrict__ idx)
{
    const int wid = blockIdx.x * 4 + (threadIdx.x >> 6);
    const int lane = threadIdx.x & 63;
    const int count = *rcount;
    for (int li = wid; li < count; li += 512 * 4) {
        const int n = rlist[li];
        const int b = n >> 10, p = n & 1023;
        const float* f = in + (size_t)b * (D * HW) + p;
        float fr[4];
        #pragma unroll
        for (int q = 0; q < 4; q++) fr[q] = f[(size_t)(lane + q * 64) * HW];
        double bm = 1e300; int bk = 0;
        #pragma unroll 1
        for (int kk = 0; kk < 16; kk++) {          // kk ascending -> lowest k on ties
            const int k = lane + kk * 64;
            const float4* er4 = (const float4*)(emb + (size_t)k * D);
            double sc[4];
            #pragma unroll
            for (int q = 0; q < 4; q++) sc[q] = 0.0;
            #pragma unroll
            for (int q = 0; q < 4; q++) {
                #pragma unroll
                for (int f4 = 0; f4 < 16; f4++) {
                    const float4 ev4 = er4[q * 16 + f4];
                    #pragma unroll
                    for (int e = 0; e < 4; e++) {
                        const int dl = f4 * 4 + e;
                        const double fv = (double)__shfl(fr[q], dl, 64);
                        const double ev = (double)((const float*)&ev4)[e];
                        sc[q] += ev * (ev - 2.0 * fv);
                    }
                }
            }
            const double s = (sc[0] + sc[1]) + (sc[2] + sc[3]);
            if (s < bm) { bm = s; bk = k; }
        }
        #pragma unroll
        for (int off = 32; off >= 1; off >>= 1) {
            double om = __shfl_xor(bm, off, 64);
            int    ok = __shfl_xor(bk, off, 64);
            if (om < bm || (om == bm && ok < bk)) { bm = om; bk = ok; }
        }
        if (lane == 0) idx[n] = bk;
    }
}

// ---- Fused outputs: qout(NCHW) + loss partials + qflat + FULL one-hot + hist ----
// Block = 32 rows x 256 d, emb rows staged in LDS (coalesced gather).
// enc is written densely here (268MB streamed) -> the separate 268MB memset pass is gone.
__global__ __launch_bounds__(256) void outputs_kernel(
    const float* __restrict__ in, const float* __restrict__ emb,
    const int* __restrict__ idx, float* __restrict__ out,
    double* __restrict__ lossPartial, int* __restrict__ hist)
{
    __shared__ int skv[32];
    __shared__ float sQ[32 * 260];
    __shared__ double sred[4];

    const int t = threadIdx.x;
    const int n0 = blockIdx.x * 32;
    const int b = n0 >> 10, p0 = n0 & 1023;

    if (t < 32) skv[t] = idx[n0 + t];
    __syncthreads();

    // stage emb rows (coalesced per 8-thread group) + write qflat directly
    {
        const int r = t >> 3, c0 = (t & 7) * 32;
        const int kv = skv[r];
        const float4* src = (const float4*)(emb + (size_t)kv * D + c0);
        float4* dstL = (float4*)(sQ + r * 260 + c0);
        float4* dstG = (float4*)(out + OUT_QFLAT + (size_t)(n0 + r) * D + c0);
        #pragma unroll
        for (int g = 0; g < 8; g++) {
            float4 v = src[g];
            dstL[g] = v;
            dstG[g] = v;
        }
    }
    // enc one-hot: dense coalesced write (thread t owns cols [4t,4t+4) of every row)
    {
        float* encBase = out + OUT_ENC + (size_t)n0 * K;
        const int c0 = t * 4;
        #pragma unroll 4
        for (int r = 0; r < 32; r++) {
            const int kv = skv[r];
            float4 v = make_float4(0.f, 0.f, 0.f, 0.f);
            if (kv >= c0 && kv < c0 + 4) ((float*)&v)[kv - c0] = 1.0f;
            *(float4*)(encBase + (size_t)r * K + c0) = v;
        }
    }
    if (t < 32) atomicAdd(&hist[skv[t]], 1);
    __syncthreads();

    // qout NCHW + loss: lanes cover p (coalesced 128B per 32-lane group)
    const int p = t & 31, dg = t >> 5;
    double acc = 0.0;
    const size_t obase = (size_t)b * (D * HW) + p0 + p;
    #pragma unroll
    for (int dd = 0; dd < 32; dd++) {
        const int d = dg * 32 + dd;
        const float q = sQ[p * 260 + d];
        const float x = in[obase + (size_t)d * HW];
        out[OUT_QOUT + obase + (size_t)d * HW] = q;
        const float df = q - x;
        acc += (double)(df * df);
    }
    #pragma unroll
    for (int off = 32; off >= 1; off >>= 1) acc += __shfl_xor(acc, off, 64);
    if ((t & 63) == 0) sred[t >> 6] = acc;
    __syncthreads();
    if (t == 0) lossPartial[blockIdx.x] = sred[0] + sred[1] + sred[2] + sred[3];
}

__global__ void finalize_kernel(const int* __restrict__ hist, const double* __restrict__ lossPartial,
                                float* __restrict__ out)
{
    const int t = threadIdx.x;
    double s = 0.0;
    #pragma unroll
    for (int q = 0; q < 4; q++) {
        const int c = hist[t + q * 256];
        const double p = (double)c / (double)NTOT;
        s += p * log(p + 1e-10);
    }
    double l = 0.0;
    #pragma unroll
    for (int q = 0; q < 8; q++) l += lossPartial[t + q * 256];
    #pragma unroll
    for (int off = 32; off >= 1; off >>= 1) {
        s += __shfl_xor(s, off, 64);
        l += __shfl_xor(l, off, 64);
    }
    __shared__ double sr[4], lr[4];
    if ((t & 63) == 0) { sr[t >> 6] = s; lr[t >> 6] = l; }
    __syncthreads();
    if (t == 0) {
        out[0] = (float)(1.25 * (lr[0] + lr[1] + lr[2] + lr[3]) / (double)(NTOT * (size_t)D));
        out[OUT_PERP] = (float)exp(-(sr[0] + sr[1] + sr[2] + sr[3]));
    }
}

extern "C" void kernel_launch(void* const* d_in, const int* in_sizes, int n_in,
                              void* d_out, int out_size, void* d_ws, size_t ws_size,
                              hipStream_t stream)
{
    const float* in  = (const float*)d_in[0];   // [64,256,32,32] fp32
    const float* emb = (const float*)d_in[1];   // [1024,256] fp32
    float* out = (float*)d_out;
    char* ws = (char*)d_ws;

    int*    rcount      = (int*)(ws + 0);
    int*    hist        = (int*)(ws + 16);
    float*  enorm       = (float*)(ws + 4112);
    int*    idx         = (int*)(ws + 8208);
    int*    rlist       = (int*)(ws + 270352);
    double* lossPartial = (double*)(ws + 532496);
    ushort* efrag       = (ushort*)(ws + 548880);

    hipMemsetAsync(ws, 0, 8208, stream);                                   // rcount + hist

    enorm_kernel<<<K / 256, 256, 0, stream>>>(emb, enorm);
    esplit_kernel<<<K / 16, 256, 0, stream>>>(emb, efrag);
    score_mfma_kernel<<<NTOT / 32, 256, 0, stream>>>(in, efrag, enorm, idx, rcount, rlist);
    rescue_kernel<<<512, 256, 0, stream>>>(in, emb, rcount, rlist, idx);
    outputs_kernel<<<NTOT / 32, 256, 0, stream>>>(in, emb, idx, out, lossPartial, hist);
    finalize_kernel<<<1, 256, 0, stream>>>(hist, lossPartial, out);
}